// Round 1
// baseline (5724.272 us; speedup 1.0000x reference)
//
#include <hip/hip_runtime.h>

#define NN 100000
#define NE 1600000
#define NG 64
#define DI 128
#define DH 256
#define DO 128

// ---------------- small utility kernels ----------------

__global__ void k_fill1(float* p, int n) {
    int i = blockIdx.x * blockDim.x + threadIdx.x;
    if (i < n) p[i] = 1.0f;
}

__global__ void k_zero(float* p, int n) {
    int i = blockIdx.x * blockDim.x + threadIdx.x;
    if (i < n) p[i] = 0.0f;
}

__global__ void k_edge_deg(const int* __restrict__ dst, float* deg, int e) {
    int i = blockIdx.x * blockDim.x + threadIdx.x;
    if (i < e) atomicAdd(&deg[dst[i]], 1.0f);
}

__global__ void k_rsqrt(float* p, int n) {
    int i = blockIdx.x * blockDim.x + threadIdx.x;
    if (i < n) p[i] = rsqrtf(p[i]);
}

// out[v][:] = feat[v][:] * dinv[v]^2   (self-loop term), D=128 fixed
__global__ void k_init_agg(const float* __restrict__ feat, const float* __restrict__ dinv,
                           float* __restrict__ out, int n) {
    int idx = blockIdx.x * blockDim.x + threadIdx.x;   // n*32 threads
    if (idx >= n * 32) return;
    int v = idx >> 5, q = idx & 31;
    float w = dinv[v];
    w *= w;
    float4 a = ((const float4*)(feat + (size_t)v * 128))[q];
    float4 r = make_float4(a.x * w, a.y * w, a.z * w, a.w * w);
    ((float4*)(out + (size_t)v * 128))[q] = r;
}

// out[dst][:] += feat[src][:] * dinv[src]*dinv[dst], D=128 fixed, 32 threads/edge
__global__ void k_edge_agg(const float* __restrict__ feat, const int* __restrict__ src,
                           const int* __restrict__ dst, const float* __restrict__ dinv,
                           float* __restrict__ out, int total) {
    int idx = blockIdx.x * blockDim.x + threadIdx.x;   // NE*32 threads
    if (idx >= total) return;
    int e = idx >> 5, q = idx & 31;
    int s = src[e], d = dst[e];
    float w = dinv[s] * dinv[d];
    float4 a = ((const float4*)(feat + (size_t)s * 128))[q];
    float* o = out + (size_t)d * 128 + q * 4;
    atomicAdd(o + 0, a.x * w);
    atomicAdd(o + 1, a.y * w);
    atomicAdd(o + 2, a.z * w);
    atomicAdd(o + 3, a.w * w);
}

// ---------------- f32 tiled GEMM: C = act(A @ B + bias) ----------------
// A: MxK row-major, B: KxN row-major. BM=BN=64, BK=16, 256 thr, 4x4/thread.
// K % 16 == 0, N % 64 == 0 required; M guarded.
__global__ __launch_bounds__(256) void k_gemm(const float* __restrict__ A,
                                              const float* __restrict__ B,
                                              const float* __restrict__ bias,
                                              float* __restrict__ C,
                                              int M, int N, int K, int relu) {
    __shared__ float As[16][68];   // transposed A tile, padded
    __shared__ float Bs[16][64];

    int tid = threadIdx.x;
    int tx = tid & 15, ty = tid >> 4;
    int bm = blockIdx.x * 64, bn = blockIdx.y * 64;

    int arow = tid >> 2;          // 0..63
    int ak0  = (tid & 3) * 4;     // 0,4,8,12
    int brow = tid >> 4;          // 0..15
    int bn0  = (tid & 15) * 4;    // 0..60

    float acc[4][4] = {};

    for (int kk = 0; kk < K; kk += 16) {
        int gr = bm + arow;
        float4 a4;
        if (gr < M) a4 = *(const float4*)(A + (size_t)gr * K + kk + ak0);
        else        a4 = make_float4(0.f, 0.f, 0.f, 0.f);
        As[ak0 + 0][arow] = a4.x;
        As[ak0 + 1][arow] = a4.y;
        As[ak0 + 2][arow] = a4.z;
        As[ak0 + 3][arow] = a4.w;

        float4 b4 = *(const float4*)(B + (size_t)(kk + brow) * N + bn + bn0);
        *(float4*)&Bs[brow][bn0] = b4;

        __syncthreads();

#pragma unroll
        for (int k = 0; k < 16; ++k) {
            float4 a = *(const float4*)&As[k][ty * 4];
            float4 b = *(const float4*)&Bs[k][tx * 4];
            float av[4] = {a.x, a.y, a.z, a.w};
            float bv[4] = {b.x, b.y, b.z, b.w};
#pragma unroll
            for (int i = 0; i < 4; ++i)
#pragma unroll
                for (int j = 0; j < 4; ++j)
                    acc[i][j] = fmaf(av[i], bv[j], acc[i][j]);
        }
        __syncthreads();
    }

    float4 bb = make_float4(0.f, 0.f, 0.f, 0.f);
    if (bias) bb = *(const float4*)(bias + bn + tx * 4);
#pragma unroll
    for (int i = 0; i < 4; ++i) {
        int r = bm + ty * 4 + i;
        if (r >= M) break;
        float4 o = make_float4(acc[i][0] + bb.x, acc[i][1] + bb.y,
                               acc[i][2] + bb.z, acc[i][3] + bb.w);
        if (relu) {
            o.x = fmaxf(o.x, 0.f); o.y = fmaxf(o.y, 0.f);
            o.z = fmaxf(o.z, 0.f); o.w = fmaxf(o.w, 0.f);
        }
        *(float4*)(C + (size_t)r * N + bn + tx * 4) = o;
    }
}

// ---------------- pooling over sorted batch ----------------
// 128 threads/block, 256 nodes/block; register accumulate, flush on graph change.
__global__ void k_pool(const float* __restrict__ feat, const int* __restrict__ batch,
                       float* __restrict__ out, float* __restrict__ cnt, int n) {
    int start = blockIdx.x * 256;
    if (start >= n) return;
    int end = min(start + 256, n);
    int c = threadIdx.x;   // 0..127

    int curg = batch[start];
    float acc = 0.f;
    int run = 0;
    for (int v = start; v < end; ++v) {
        int g = batch[v];
        if (g != curg) {
            atomicAdd(&out[curg * 128 + c], acc);
            if (c == 0) atomicAdd(&cnt[curg], (float)run);
            acc = 0.f; run = 0; curg = g;
        }
        acc += feat[(size_t)v * 128 + c];
        run++;
    }
    atomicAdd(&out[curg * 128 + c], acc);
    if (c == 0) atomicAdd(&cnt[curg], (float)run);
}

__global__ void k_biasfix(const float* __restrict__ bias, const float* __restrict__ cnt,
                          float* __restrict__ out) {
    int idx = blockIdx.x * blockDim.x + threadIdx.x;   // NG*128
    if (idx >= NG * 128) return;
    int g = idx >> 7, c = idx & 127;
    out[idx] += bias[c] * cnt[g];
}

// ---------------- launch ----------------

extern "C" void kernel_launch(void* const* d_in, const int* in_sizes, int n_in,
                              void* d_out, int out_size, void* d_ws, size_t ws_size,
                              hipStream_t stream) {
    const float* x     = (const float*)d_in[0];
    const int*   ei    = (const int*)d_in[1];
    const int*   batch = (const int*)d_in[2];
    const float* W1    = (const float*)d_in[3];
    const float* b1    = (const float*)d_in[4];
    const float* W2    = (const float*)d_in[5];
    const float* b2    = (const float*)d_in[6];
    float* out = (float*)d_out;

    const int* src = ei;
    const int* dst = ei + NE;

    char* ws = (char*)d_ws;
    float* dinv = (float*)ws;                                  // 0.4 MB (pad 1 MiB)
    float* bufA = (float*)(ws + (1u << 20));                   // 51.2 MB (agg1, then t)
    float* bufB = (float*)(ws + (1u << 20) + 52428800u);       // 102.4 MB (h1, then agg2)
    float* cnt  = (float*)(ws + (1u << 20) + 52428800u + 104857600u);  // 64 floats

    const int BLK = 256;
    auto cdiv = [](int a, int b) { return (a + b - 1) / b; };

    // degrees -> dinv
    k_fill1<<<cdiv(NN, BLK), BLK, 0, stream>>>(dinv, NN);
    k_edge_deg<<<cdiv(NE, BLK), BLK, 0, stream>>>(dst, dinv, NE);
    k_rsqrt<<<cdiv(NN, BLK), BLK, 0, stream>>>(dinv, NN);

    // agg1 = A_hat @ x  (D=128)
    k_init_agg<<<cdiv(NN * 32, BLK), BLK, 0, stream>>>(x, dinv, bufA, NN);
    k_edge_agg<<<cdiv(NE * 32, BLK), BLK, 0, stream>>>(x, src, dst, dinv, bufA, NE * 32);

    // h1 = relu(agg1 @ W1 + b1)   (100000x128 @ 128x256)
    {
        dim3 grid(cdiv(NN, 64), DH / 64);
        k_gemm<<<grid, 256, 0, stream>>>(bufA, W1, b1, bufB, NN, DH, DI, 1);
    }

    // t = h1 @ W2   (100000x256 @ 256x128), no bias
    {
        dim3 grid(cdiv(NN, 64), DO / 64);
        k_gemm<<<grid, 256, 0, stream>>>(bufB, W2, nullptr, bufA, NN, DO, DH, 0);
    }

    // agg2 = A_hat @ t  (D=128), into bufB
    k_init_agg<<<cdiv(NN * 32, BLK), BLK, 0, stream>>>(bufA, dinv, bufB, NN);
    k_edge_agg<<<cdiv(NE * 32, BLK), BLK, 0, stream>>>(bufA, src, dst, dinv, bufB, NE * 32);

    // pool + bias fixup
    k_zero<<<cdiv(NG * 128, BLK), BLK, 0, stream>>>(out, NG * 128);
    k_zero<<<1, 64, 0, stream>>>(cnt, NG);
    k_pool<<<cdiv(NN, 256), 128, 0, stream>>>(bufB, batch, out, cnt, NN);
    k_biasfix<<<cdiv(NG * 128, BLK), BLK, 0, stream>>>(b2, cnt, out);
}

// Round 2
// 710.429 us; speedup vs baseline: 8.0575x; 8.0575x over previous
//
#include <hip/hip_runtime.h>

#define NN 100000
#define NE 1600000
#define NG 64
#define DI 128
#define DH 256
#define DO 128

// ---------------- small utility kernels ----------------

__global__ void k_zero(float* p, int n) {
    int i = blockIdx.x * blockDim.x + threadIdx.x;
    if (i < n) p[i] = 0.0f;
}

__global__ void k_zero_int(int* p, int n) {
    int i = blockIdx.x * blockDim.x + threadIdx.x;
    if (i < n) p[i] = 0;
}

__global__ void k_hist(const int* __restrict__ dst, int* __restrict__ cnt, int e) {
    int i = blockIdx.x * blockDim.x + threadIdx.x;
    if (i < e) atomicAdd(&cnt[dst[i]], 1);
}

__global__ void k_dinv(const int* __restrict__ cnt_in, float* __restrict__ dinv, int n) {
    int i = blockIdx.x * blockDim.x + threadIdx.x;
    if (i < n) dinv[i] = rsqrtf((float)(cnt_in[i] + 1));   // +1 self-loop
}

__global__ void k_copy_int(const int* __restrict__ a, int* __restrict__ b, int n) {
    int i = blockIdx.x * blockDim.x + threadIdx.x;
    if (i < n) b[i] = a[i];
}

// ---------------- exclusive scan (2-level) ----------------

__global__ void k_scan1(const int* __restrict__ in, int* __restrict__ out,
                        int* __restrict__ bsum, int n) {
    __shared__ int sh[256];
    int t = threadIdx.x;
    int i = blockIdx.x * 256 + t;
    int v = (i < n) ? in[i] : 0;
    sh[t] = v;
    __syncthreads();
    for (int off = 1; off < 256; off <<= 1) {
        int add = (t >= off) ? sh[t - off] : 0;
        __syncthreads();
        sh[t] += add;
        __syncthreads();
    }
    if (i < n) out[i] = sh[t] - v;              // exclusive within block
    if (t == 255) bsum[blockIdx.x] = sh[255];
}

__global__ void k_scan2(int* __restrict__ bsum, int nb) {
    __shared__ int sh[512];
    int t = threadIdx.x;
    int v = (t < nb) ? bsum[t] : 0;
    sh[t] = v;
    __syncthreads();
    for (int off = 1; off < 512; off <<= 1) {
        int add = (t >= off) ? sh[t - off] : 0;
        __syncthreads();
        sh[t] += add;
        __syncthreads();
    }
    if (t < nb) bsum[t] = sh[t] - v;            // exclusive block offsets
}

__global__ void k_scan3(int* __restrict__ out, const int* __restrict__ bsum,
                        int n, int total) {
    int i = blockIdx.x * 256 + threadIdx.x;
    if (i < n) out[i] += bsum[blockIdx.x];
    if (i == 0) out[n] = total;
}

// ---------------- CSR fill ----------------

__global__ void k_fill_csr(const int* __restrict__ src, const int* __restrict__ dst,
                           int* __restrict__ cursor, int* __restrict__ csr_src, int e) {
    int i = blockIdx.x * blockDim.x + threadIdx.x;
    if (i < e) {
        int pos = atomicAdd(&cursor[dst[i]], 1);
        csr_src[pos] = src[i];
    }
}

// ---------------- gather aggregation: out = A_hat @ feat (D=128) ----------------
// 32 lanes per node; float4 per lane; register accumulate; one plain store.
__global__ __launch_bounds__(256) void k_agg(const float* __restrict__ feat,
        const int* __restrict__ csr_src, const int* __restrict__ row_start,
        const float* __restrict__ dinv, float* __restrict__ out, int n) {
    int gid = blockIdx.x * blockDim.x + threadIdx.x;
    int node = gid >> 5;
    int lane = threadIdx.x & 31;
    if (node >= n) return;
    float wd = dinv[node];
    const float4* f4 = (const float4*)feat;
    float4 a = f4[(size_t)node * 32 + lane];
    float4 acc = make_float4(a.x * wd, a.y * wd, a.z * wd, a.w * wd);  // self term
    int j = row_start[node], end = row_start[node + 1];
    for (; j + 1 < end; j += 2) {
        int s0 = csr_src[j], s1 = csr_src[j + 1];
        float w0 = dinv[s0], w1 = dinv[s1];
        float4 v0 = f4[(size_t)s0 * 32 + lane];
        float4 v1 = f4[(size_t)s1 * 32 + lane];
        acc.x += w0 * v0.x + w1 * v1.x;
        acc.y += w0 * v0.y + w1 * v1.y;
        acc.z += w0 * v0.z + w1 * v1.z;
        acc.w += w0 * v0.w + w1 * v1.w;
    }
    if (j < end) {
        int s = csr_src[j];
        float w = dinv[s];
        float4 v = f4[(size_t)s * 32 + lane];
        acc.x += w * v.x; acc.y += w * v.y; acc.z += w * v.z; acc.w += w * v.w;
    }
    acc.x *= wd; acc.y *= wd; acc.z *= wd; acc.w *= wd;
    ((float4*)out)[(size_t)node * 32 + lane] = acc;
}

// ---------------- f32 tiled GEMM: C = act(A @ B + bias) ----------------
__global__ __launch_bounds__(256) void k_gemm(const float* __restrict__ A,
                                              const float* __restrict__ B,
                                              const float* __restrict__ bias,
                                              float* __restrict__ C,
                                              int M, int N, int K, int relu) {
    __shared__ float As[16][68];   // transposed A tile, padded
    __shared__ float Bs[16][64];

    int tid = threadIdx.x;
    int tx = tid & 15, ty = tid >> 4;
    int bm = blockIdx.x * 64, bn = blockIdx.y * 64;

    int arow = tid >> 2;          // 0..63
    int ak0  = (tid & 3) * 4;     // 0,4,8,12
    int brow = tid >> 4;          // 0..15
    int bn0  = (tid & 15) * 4;    // 0..60

    float acc[4][4] = {};

    for (int kk = 0; kk < K; kk += 16) {
        int gr = bm + arow;
        float4 a4;
        if (gr < M) a4 = *(const float4*)(A + (size_t)gr * K + kk + ak0);
        else        a4 = make_float4(0.f, 0.f, 0.f, 0.f);
        As[ak0 + 0][arow] = a4.x;
        As[ak0 + 1][arow] = a4.y;
        As[ak0 + 2][arow] = a4.z;
        As[ak0 + 3][arow] = a4.w;

        float4 b4 = *(const float4*)(B + (size_t)(kk + brow) * N + bn + bn0);
        *(float4*)&Bs[brow][bn0] = b4;

        __syncthreads();

#pragma unroll
        for (int k = 0; k < 16; ++k) {
            float4 a = *(const float4*)&As[k][ty * 4];
            float4 b = *(const float4*)&Bs[k][tx * 4];
            float av[4] = {a.x, a.y, a.z, a.w};
            float bv[4] = {b.x, b.y, b.z, b.w};
#pragma unroll
            for (int i = 0; i < 4; ++i)
#pragma unroll
                for (int j = 0; j < 4; ++j)
                    acc[i][j] = fmaf(av[i], bv[j], acc[i][j]);
        }
        __syncthreads();
    }

    float4 bb = make_float4(0.f, 0.f, 0.f, 0.f);
    if (bias) bb = *(const float4*)(bias + bn + tx * 4);
#pragma unroll
    for (int i = 0; i < 4; ++i) {
        int r = bm + ty * 4 + i;
        if (r >= M) break;
        float4 o = make_float4(acc[i][0] + bb.x, acc[i][1] + bb.y,
                               acc[i][2] + bb.z, acc[i][3] + bb.w);
        if (relu) {
            o.x = fmaxf(o.x, 0.f); o.y = fmaxf(o.y, 0.f);
            o.z = fmaxf(o.z, 0.f); o.w = fmaxf(o.w, 0.f);
        }
        *(float4*)(C + (size_t)r * N + bn + tx * 4) = o;
    }
}

// ---------------- pooling over sorted batch ----------------

__global__ void k_pool(const float* __restrict__ feat, const int* __restrict__ batch,
                       float* __restrict__ out, float* __restrict__ cnt, int n) {
    int start = blockIdx.x * 256;
    if (start >= n) return;
    int end = min(start + 256, n);
    int c = threadIdx.x;   // 0..127

    int curg = batch[start];
    float acc = 0.f;
    int run = 0;
    for (int v = start; v < end; ++v) {
        int g = batch[v];
        if (g != curg) {
            atomicAdd(&out[curg * 128 + c], acc);
            if (c == 0) atomicAdd(&cnt[curg], (float)run);
            acc = 0.f; run = 0; curg = g;
        }
        acc += feat[(size_t)v * 128 + c];
        run++;
    }
    atomicAdd(&out[curg * 128 + c], acc);
    if (c == 0) atomicAdd(&cnt[curg], (float)run);
}

__global__ void k_biasfix(const float* __restrict__ bias, const float* __restrict__ cnt,
                          float* __restrict__ out) {
    int idx = blockIdx.x * blockDim.x + threadIdx.x;   // NG*128
    if (idx >= NG * 128) return;
    int g = idx >> 7, c = idx & 127;
    out[idx] += bias[c] * cnt[g];
}

// ---------------- launch ----------------

extern "C" void kernel_launch(void* const* d_in, const int* in_sizes, int n_in,
                              void* d_out, int out_size, void* d_ws, size_t ws_size,
                              hipStream_t stream) {
    const float* x     = (const float*)d_in[0];
    const int*   ei    = (const int*)d_in[1];
    const int*   batch = (const int*)d_in[2];
    const float* W1    = (const float*)d_in[3];
    const float* b1    = (const float*)d_in[4];
    const float* W2    = (const float*)d_in[5];
    const float* b2    = (const float*)d_in[6];
    float* out = (float*)d_out;

    const int* src = ei;
    const int* dst = ei + NE;

    // workspace layout (16B aligned), total ~161.3 MB
    char* ws = (char*)d_ws;
    float* dinv   = (float*)(ws);               // 400,000 B
    int*   cnt_in = (int*)(ws + 400000);        // 400,000 B (reused as cursor)
    int*   rowst  = (int*)(ws + 800000);        // 400,004 B (NN+1)
    int*   bsum   = (int*)(ws + 1200016);       // 1,564 B
    float* cnt    = (float*)(ws + 1203200);     // 256 B
    int*   csr    = (int*)(ws + 1203712);       // 6,400,000 B
    float* bufA   = (float*)(ws + 7603712);     // 51,200,000 B  (agg1, then t)
    float* bufB   = (float*)(ws + 58803712);    // 102,400,000 B (h1, then agg2)

    const int BLK = 256;
    auto cdiv = [](int a, int b) { return (a + b - 1) / b; };
    const int NB = cdiv(NN, 256);   // 391 scan blocks

    // ---- degree + CSR build (shared by both layers) ----
    k_zero_int<<<cdiv(NN, BLK), BLK, 0, stream>>>(cnt_in, NN);
    k_hist<<<cdiv(NE, BLK), BLK, 0, stream>>>(dst, cnt_in, NE);
    k_scan1<<<NB, 256, 0, stream>>>(cnt_in, rowst, bsum, NN);
    k_scan2<<<1, 512, 0, stream>>>(bsum, NB);
    k_scan3<<<NB, 256, 0, stream>>>(rowst, bsum, NN, NE);
    k_dinv<<<cdiv(NN, BLK), BLK, 0, stream>>>(cnt_in, dinv, NN);
    k_copy_int<<<cdiv(NN, BLK), BLK, 0, stream>>>(rowst, cnt_in, NN);  // cursor
    k_fill_csr<<<cdiv(NE, BLK), BLK, 0, stream>>>(src, dst, cnt_in, csr, NE);

    // ---- layer 1: agg1 = A_hat @ x ; h1 = relu(agg1 @ W1 + b1) ----
    k_agg<<<cdiv(NN * 32, BLK), BLK, 0, stream>>>(x, csr, rowst, dinv, bufA, NN);
    {
        dim3 grid(cdiv(NN, 64), DH / 64);
        k_gemm<<<grid, 256, 0, stream>>>(bufA, W1, b1, bufB, NN, DH, DI, 1);
    }

    // ---- layer 2: t = h1 @ W2 ; agg2 = A_hat @ t ----
    {
        dim3 grid(cdiv(NN, 64), DO / 64);
        k_gemm<<<grid, 256, 0, stream>>>(bufB, W2, nullptr, bufA, NN, DO, DH, 0);
    }
    k_agg<<<cdiv(NN * 32, BLK), BLK, 0, stream>>>(bufA, csr, rowst, dinv, bufB, NN);

    // ---- pool + bias fixup ----
    k_zero<<<cdiv(NG * 128, BLK), BLK, 0, stream>>>(out, NG * 128);
    k_zero<<<1, 64, 0, stream>>>(cnt, NG);
    k_pool<<<cdiv(NN, 256), 128, 0, stream>>>(bufB, batch, out, cnt, NN);
    k_biasfix<<<cdiv(NG * 128, BLK), BLK, 0, stream>>>(b2, cnt, out);
}

// Round 3
// 500.206 us; speedup vs baseline: 11.4438x; 1.4203x over previous
//
#include <hip/hip_runtime.h>

#define NN 100000
#define NE 1600000
#define NG 64
#define DI 128
#define DH 256
#define DO 128

using short8 = __attribute__((ext_vector_type(8))) short;
using f32x4  = __attribute__((ext_vector_type(4))) float;

__device__ __forceinline__ float bf2f(unsigned short u) {
    return __uint_as_float(((unsigned)u) << 16);
}
__device__ __forceinline__ unsigned short f2bf(float f) {
    unsigned u = __float_as_uint(f);
    unsigned r = (u + 0x7FFFu + ((u >> 16) & 1u)) >> 16;   // RNE
    return (unsigned short)r;
}

// ---------------- small utility kernels ----------------

__global__ void k_zero(float* p, int n) {
    int i = blockIdx.x * blockDim.x + threadIdx.x;
    if (i < n) p[i] = 0.0f;
}
__global__ void k_zero_int(int* p, int n) {
    int i = blockIdx.x * blockDim.x + threadIdx.x;
    if (i < n) p[i] = 0;
}
__global__ void k_hist(const int* __restrict__ dst, int* __restrict__ cnt, int e) {
    int i = blockIdx.x * blockDim.x + threadIdx.x;
    if (i < e) atomicAdd(&cnt[dst[i]], 1);
}
__global__ void k_dinv(const int* __restrict__ cnt_in, float* __restrict__ dinv, int n) {
    int i = blockIdx.x * blockDim.x + threadIdx.x;
    if (i < n) dinv[i] = rsqrtf((float)(cnt_in[i] + 1));
}
__global__ void k_copy_int(const int* __restrict__ a, int* __restrict__ b, int n) {
    int i = blockIdx.x * blockDim.x + threadIdx.x;
    if (i < n) b[i] = a[i];
}

// f32 -> bf16 bulk convert (4 elems/thread)
__global__ void k_cvt_bf(const float* __restrict__ in, unsigned short* __restrict__ out, int n4) {
    int i = blockIdx.x * blockDim.x + threadIdx.x;
    if (i >= n4) return;
    float4 v = ((const float4*)in)[i];
    ushort4 o;
    o.x = f2bf(v.x); o.y = f2bf(v.y); o.z = f2bf(v.z); o.w = f2bf(v.w);
    ((ushort4*)out)[i] = o;
}

// W (KxN f32, row-major) -> Wt (NxK bf16)
__global__ void k_wt(const float* __restrict__ W, unsigned short* __restrict__ Wt, int K, int N) {
    int i = blockIdx.x * blockDim.x + threadIdx.x;
    if (i >= K * N) return;
    int k = i / N, n = i % N;
    Wt[n * K + k] = f2bf(W[i]);
}

// ---------------- exclusive scan (2-level) ----------------

__global__ void k_scan1(const int* __restrict__ in, int* __restrict__ out,
                        int* __restrict__ bsum, int n) {
    __shared__ int sh[256];
    int t = threadIdx.x;
    int i = blockIdx.x * 256 + t;
    int v = (i < n) ? in[i] : 0;
    sh[t] = v;
    __syncthreads();
    for (int off = 1; off < 256; off <<= 1) {
        int add = (t >= off) ? sh[t - off] : 0;
        __syncthreads();
        sh[t] += add;
        __syncthreads();
    }
    if (i < n) out[i] = sh[t] - v;
    if (t == 255) bsum[blockIdx.x] = sh[255];
}
__global__ void k_scan2(int* __restrict__ bsum, int nb) {
    __shared__ int sh[512];
    int t = threadIdx.x;
    int v = (t < nb) ? bsum[t] : 0;
    sh[t] = v;
    __syncthreads();
    for (int off = 1; off < 512; off <<= 1) {
        int add = (t >= off) ? sh[t - off] : 0;
        __syncthreads();
        sh[t] += add;
        __syncthreads();
    }
    if (t < nb) bsum[t] = sh[t] - v;
}
__global__ void k_scan3(int* __restrict__ out, const int* __restrict__ bsum,
                        int n, int total) {
    int i = blockIdx.x * 256 + threadIdx.x;
    if (i < n) out[i] += bsum[blockIdx.x];
    if (i == 0) out[n] = total;
}

// ---------------- CSR fill: dst-range pass for write locality ----------------

__global__ void k_fill_csr(const int* __restrict__ src, const int* __restrict__ dst,
                           int* __restrict__ cursor, int* __restrict__ csr_src,
                           int e, int lo, int hi) {
    int i = blockIdx.x * blockDim.x + threadIdx.x;
    if (i < e) {
        int d = dst[i];
        if (d >= lo && d < hi) {
            int pos = atomicAdd(&cursor[d], 1);
            csr_src[pos] = src[i];
        }
    }
}

// ---------------- gather aggregation (bf16 feat): out = A_hat @ feat, D=128 ----------------
template<bool OUT_BF>
__global__ __launch_bounds__(256) void k_agg(const unsigned short* __restrict__ feat,
        const int* __restrict__ csr_src, const int* __restrict__ row_start,
        const float* __restrict__ dinv, void* __restrict__ outv, int n) {
    int gid = blockIdx.x * blockDim.x + threadIdx.x;
    int node = gid >> 5;
    int lane = threadIdx.x & 31;
    if (node >= n) return;
    const ushort4* f4 = (const ushort4*)feat;
    float wd = dinv[node];
    ushort4 a = f4[(size_t)node * 32 + lane];
    float4 acc;
    acc.x = bf2f(a.x) * wd; acc.y = bf2f(a.y) * wd;
    acc.z = bf2f(a.z) * wd; acc.w = bf2f(a.w) * wd;
    int j = row_start[node], end = row_start[node + 1];
    for (; j + 1 < end; j += 2) {
        int s0 = csr_src[j], s1 = csr_src[j + 1];
        float w0 = dinv[s0], w1 = dinv[s1];
        ushort4 v0 = f4[(size_t)s0 * 32 + lane];
        ushort4 v1 = f4[(size_t)s1 * 32 + lane];
        acc.x += w0 * bf2f(v0.x) + w1 * bf2f(v1.x);
        acc.y += w0 * bf2f(v0.y) + w1 * bf2f(v1.y);
        acc.z += w0 * bf2f(v0.z) + w1 * bf2f(v1.z);
        acc.w += w0 * bf2f(v0.w) + w1 * bf2f(v1.w);
    }
    if (j < end) {
        int s = csr_src[j];
        float w = dinv[s];
        ushort4 v = f4[(size_t)s * 32 + lane];
        acc.x += w * bf2f(v.x); acc.y += w * bf2f(v.y);
        acc.z += w * bf2f(v.z); acc.w += w * bf2f(v.w);
    }
    acc.x *= wd; acc.y *= wd; acc.z *= wd; acc.w *= wd;
    if (OUT_BF) {
        ushort4 o;
        o.x = f2bf(acc.x); o.y = f2bf(acc.y); o.z = f2bf(acc.z); o.w = f2bf(acc.w);
        ((ushort4*)outv)[(size_t)node * 32 + lane] = o;
    } else {
        ((float4*)outv)[(size_t)node * 32 + lane] = acc;
    }
}

// ---------------- bf16 MFMA GEMM: C = act(A @ Bt^T + bias), BM=128, 512 thr ----------------
// A: MxK bf16 row-major. Bt: NxK bf16 (pre-transposed weights). C: MxN bf16.
template<int K, int N, bool RELU, bool BIAS>
__global__ __launch_bounds__(512) void k_gemm_bf(const unsigned short* __restrict__ A,
        const unsigned short* __restrict__ Bt, const float* __restrict__ bias,
        unsigned short* __restrict__ C, int M) {
    constexpr int BM = 128;
    __shared__ unsigned short As[BM * K];   // XOR-swizzled rows
    __shared__ unsigned short Bs[N * K];    // XOR-swizzled rows (col-major wrt B)

    const int tid = threadIdx.x;
    const int bm = blockIdx.x * BM;

    // stage A (BM x K), 16B chunks
    constexpr int AC = BM * K / 8;
    for (int c = tid; c < AC; c += 512) {
        int row = c / (K / 8);
        int kc  = (c % (K / 8)) * 8;
        uint4 v = make_uint4(0, 0, 0, 0);
        int gr = bm + row;
        if (gr < M) v = *(const uint4*)(A + (size_t)gr * K + kc);
        int byte = row * (2 * K) + ((kc * 2) ^ ((row & 7) << 4));
        *(uint4*)((char*)As + byte) = v;
    }
    // stage Bt (N x K)
    constexpr int BC = N * K / 8;
    for (int c = tid; c < BC; c += 512) {
        int col = c / (K / 8);
        int kc  = (c % (K / 8)) * 8;
        uint4 v = *(const uint4*)(Bt + (size_t)col * K + kc);
        int byte = col * (2 * K) + ((kc * 2) ^ ((col & 7) << 4));
        *(uint4*)((char*)Bs + byte) = v;
    }
    __syncthreads();

    const int w  = tid >> 6;        // wave 0..7 -> 16 rows each
    const int l  = tid & 63;
    const int lr = l & 15;
    const int lg = l >> 4;
    const int r0 = w * 16;

    constexpr int NT = N / 16;
    f32x4 acc[NT] = {};

    const int arow  = r0 + lr;
    const int abase = arow * (2 * K);
    const int aswz  = (arow & 7) << 4;

#pragma unroll
    for (int ks = 0; ks < K / 32; ++ks) {
        int kb = ks * 64 + lg * 16;
        short8 a = *(const short8*)((const char*)As + abase + (kb ^ aswz));
#pragma unroll
        for (int n = 0; n < NT; ++n) {
            int col = n * 16 + lr;
            short8 b = *(const short8*)((const char*)Bs + col * (2 * K) + (kb ^ ((col & 7) << 4)));
            acc[n] = __builtin_amdgcn_mfma_f32_16x16x32_bf16(a, b, acc[n], 0, 0, 0);
        }
    }

#pragma unroll
    for (int n = 0; n < NT; ++n) {
        int col = n * 16 + lr;
        float bb = BIAS ? bias[col] : 0.0f;
#pragma unroll
        for (int r = 0; r < 4; ++r) {
            int row = bm + r0 + lg * 4 + r;   // C/D: col=lane&15, row=(lane>>4)*4+reg
            if (row < M) {
                float v = acc[n][r] + bb;
                if (RELU) v = fmaxf(v, 0.f);
                C[(size_t)row * N + col] = f2bf(v);
            }
        }
    }
}

// ---------------- pooling over sorted batch (f32 input) ----------------

__global__ void k_pool(const float* __restrict__ feat, const int* __restrict__ batch,
                       float* __restrict__ out, float* __restrict__ cnt, int n) {
    int start = blockIdx.x * 256;
    if (start >= n) return;
    int end = min(start + 256, n);
    int c = threadIdx.x;   // 0..127

    int curg = batch[start];
    float acc = 0.f;
    int run = 0;
    for (int v = start; v < end; ++v) {
        int g = batch[v];
        if (g != curg) {
            atomicAdd(&out[curg * 128 + c], acc);
            if (c == 0) atomicAdd(&cnt[curg], (float)run);
            acc = 0.f; run = 0; curg = g;
        }
        acc += feat[(size_t)v * 128 + c];
        run++;
    }
    atomicAdd(&out[curg * 128 + c], acc);
    if (c == 0) atomicAdd(&cnt[curg], (float)run);
}

__global__ void k_biasfix(const float* __restrict__ bias, const float* __restrict__ cnt,
                          float* __restrict__ out) {
    int idx = blockIdx.x * blockDim.x + threadIdx.x;
    if (idx >= NG * 128) return;
    int g = idx >> 7, c = idx & 127;
    out[idx] += bias[c] * cnt[g];
}

// ---------------- launch ----------------

extern "C" void kernel_launch(void* const* d_in, const int* in_sizes, int n_in,
                              void* d_out, int out_size, void* d_ws, size_t ws_size,
                              hipStream_t stream) {
    const float* x     = (const float*)d_in[0];
    const int*   ei    = (const int*)d_in[1];
    const int*   batch = (const int*)d_in[2];
    const float* W1    = (const float*)d_in[3];
    const float* b1    = (const float*)d_in[4];
    const float* W2    = (const float*)d_in[5];
    const float* b2    = (const float*)d_in[6];
    float* out = (float*)d_out;

    const int* src = ei;
    const int* dst = ei + NE;

    // workspace layout (all 16B aligned), ~136.4 MB total
    char* ws = (char*)d_ws;
    float*          dinv   = (float*)(ws + 0);
    int*            cnt_in = (int*)(ws + 524288);
    int*            rowst  = (int*)(ws + 1048576);
    int*            bsum   = (int*)(ws + 1572864);
    float*          cnt    = (float*)(ws + 1576960);
    unsigned short* w1t    = (unsigned short*)(ws + 1581056);   // 256x128 bf16
    unsigned short* w2t    = (unsigned short*)(ws + 1646592);   // 128x256 bf16
    int*            csr    = (int*)(ws + 1712128);              // 6.4 MB
    unsigned short* xbf    = (unsigned short*)(ws + 8388608);   // 25.6 MB
    unsigned short* agg1   = (unsigned short*)(ws + 33988608);  // 25.6 MB
    float*          agg2   = (float*)(ws + 8388608);            // 51.2 MB (reuses xbf+agg1)
    unsigned short* h1     = (unsigned short*)(ws + 59588608);  // 51.2 MB
    unsigned short* tbf    = (unsigned short*)(ws + 110788608); // 25.6 MB

    const int BLK = 256;
    auto cdiv = [](int a, int b) { return (a + b - 1) / b; };
    const int NB = cdiv(NN, 256);

    // ---- conversions (independent of graph build) ----
    k_cvt_bf<<<cdiv(NN * 32, BLK), BLK, 0, stream>>>(x, xbf, NN * 32);   // 12.8M elems / 4
    k_wt<<<cdiv(DI * DH, BLK), BLK, 0, stream>>>(W1, w1t, DI, DH);
    k_wt<<<cdiv(DH * DO, BLK), BLK, 0, stream>>>(W2, w2t, DH, DO);

    // ---- degree + CSR build ----
    k_zero_int<<<cdiv(NN, BLK), BLK, 0, stream>>>(cnt_in, NN);
    k_hist<<<cdiv(NE, BLK), BLK, 0, stream>>>(dst, cnt_in, NE);
    k_scan1<<<NB, 256, 0, stream>>>(cnt_in, rowst, bsum, NN);
    k_scan2<<<1, 512, 0, stream>>>(bsum, NB);
    k_scan3<<<NB, 256, 0, stream>>>(rowst, bsum, NN, NE);
    k_dinv<<<cdiv(NN, BLK), BLK, 0, stream>>>(cnt_in, dinv, NN);
    k_copy_int<<<cdiv(NN, BLK), BLK, 0, stream>>>(rowst, cnt_in, NN);   // cursor
    {
        const int NPASS = 4, NPP = (NN + NPASS - 1) / NPASS;
        for (int p = 0; p < NPASS; ++p)
            k_fill_csr<<<cdiv(NE, BLK), BLK, 0, stream>>>(src, dst, cnt_in, csr, NE,
                                                          p * NPP, (p + 1) * NPP);
    }

    // ---- layer 1: agg1 = A_hat @ x (bf16) ; h1 = relu(agg1 @ W1 + b1) (bf16) ----
    k_agg<true><<<cdiv(NN * 32, BLK), BLK, 0, stream>>>(xbf, csr, rowst, dinv, agg1, NN);
    k_gemm_bf<DI, DH, true, true><<<cdiv(NN, 128), 512, 0, stream>>>(agg1, w1t, b1, h1, NN);

    // ---- layer 2: t = h1 @ W2 (bf16) ; agg2 = A_hat @ t (f32 out) ----
    k_gemm_bf<DH, DO, false, false><<<cdiv(NN, 128), 512, 0, stream>>>(h1, w2t, nullptr, tbf, NN);
    k_agg<false><<<cdiv(NN * 32, BLK), BLK, 0, stream>>>(tbf, csr, rowst, dinv, agg2, NN);

    // ---- pool + bias fixup ----
    k_zero<<<cdiv(NG * 128, BLK), BLK, 0, stream>>>(out, NG * 128);
    k_zero<<<1, 64, 0, stream>>>(cnt, NG);
    k_pool<<<cdiv(NN, 256), 128, 0, stream>>>(agg2, batch, out, cnt, NN);
    k_biasfix<<<cdiv(NG * 128, BLK), BLK, 0, stream>>>(b2, cnt, out);
}